// Round 6
// baseline (239.796 us; speedup 1.0000x reference)
//
#include <hip/hip_runtime.h>

// TorchPatchNN: unfold(7x7) -> NN argmin over 8100 keys (D=147) -> gather value -> fold mean.
// Round 6: barrier-free K-loop. R5's 34% MfmaUtil was a barrier convoy (all 8 waves/CU sync
// per chunk -> LDS phase and MFMA phase serialize). Now: Q frags persistent in VGPRs (160),
// B frags global->VGPR per chunk (coalesced dwordx4 from frag-order layout), NO LDS / NO
// __syncthreads in the main loop. 512 persistent blocks (2/CU), each sweeps 8 kt tiles;
// running argmin in regs, one packed-u64 atomicMin per q at block end.
// Numerics unchanged (fp16 h + 2^-11*l split, 3 MFMA passes): absmax has been 0 for 3 rounds.

#define NQ 8100
#define NK 8100
#define DD 147
#define HO 90
#define IMG 96
#define NCH 5                 // K chunks of 32 (160 padded K)
#define CST 262144            // f16 per chunk plane: 512 groups x 512
#define ARRN (NCH * CST)      // f16 per array

typedef _Float16 half8 __attribute__((ext_vector_type(8)));
typedef float f32x4 __attribute__((ext_vector_type(4)));

// ---------------- prep: split Q/K into fp16 hi/lo (frag order) + key norms + init ---------
__global__ void k_prep(const float* __restrict__ query, const float* __restrict__ key,
                       _Float16* __restrict__ Qh, _Float16* __restrict__ Ql,
                       _Float16* __restrict__ Kh, _Float16* __restrict__ Kl,
                       float* __restrict__ kn, unsigned long long* __restrict__ fidx64) {
    const int bx = blockIdx.x;
    const bool isK = (blockIdx.y != 0);

    if (bx >= 640) {                      // fused k_kn region: 128 blocks on y==1
        if (!isK) return;
        int wave = threadIdx.x >> 6, lane = threadIdx.x & 63;
        int kb = ((bx - 640) * 4 + wave) * 16;
        for (int r = 0; r < 16; ++r) {
            int k = kb + r;
            float s = 0.f;
            if (k < NK)
                for (int d = lane; d < DD; d += 64) {
                    float v = key[k * DD + d];
                    s += v * v;
                }
#pragma unroll
            for (int off = 32; off; off >>= 1) s += __shfl_down(s, off, 64);
            if (lane == 0) {
                kn[k] = (k < NK) ? s : 1e30f;
                fidx64[k] = 0xFFFFFFFFFFFFFFFFull;   // ws re-poisoned every launch
            }
        }
        return;
    }

    int t = bx * 256 + threadIdx.x;             // 0 .. 163839 (ARRN/8)
    int c = t >> 15;                            // chunk
    int rem = t & 32767;                        // g*64 + lane
    int col = ((rem >> 6) << 4) + (rem & 15);   // g*16 + l15
    int quad = (rem >> 4) & 3;
    int kbase = c * 32 + quad * 8;

    float v[8];
#pragma unroll
    for (int j = 0; j < 8; ++j) {
        int k = kbase + j;
        float x = 0.f;
        if (k < DD && col < NQ) {
            if (isK) {
                x = key[col * DD + k];
            } else {
                int c3 = k / 49, r2 = k - 49 * c3;
                int rr = r2 / 7, ss = r2 - 7 * rr;
                int y = col / HO, xx = col - HO * y;
                x = query[(c3 * IMG + y + rr) * IMG + xx + ss];
            }
        }
        v[j] = x;
    }
    half8 h8, l8;
#pragma unroll
    for (int j = 0; j < 8; ++j) {
        _Float16 h = (_Float16)v[j];
        h8[j] = h;
        l8[j] = (_Float16)((v[j] - (float)h) * 2048.0f);
    }
    if (isK) {
        *(half8*)(Kh + t * 8) = h8;
        *(half8*)(Kl + t * 8) = l8;
    } else {
        *(half8*)(Qh + t * 8) = h8;
        *(half8*)(Ql + t * 8) = l8;
    }
}

// ---------------- main: split-f16 MFMA Q.K^T + fused argmin, barrier-free K-loop ----------
__launch_bounds__(256, 2)
__global__ void k_nn(const _Float16* __restrict__ Qh, const _Float16* __restrict__ Ql,
                     const _Float16* __restrict__ Kh, const _Float16* __restrict__ Kl,
                     const float* __restrict__ kn, unsigned long long* __restrict__ out) {
    __shared__ float redv[128 * 33];   // stride-33 pad: conflict-free scan
    __shared__ int   redi[128 * 33];

    const int tid = (int)threadIdx.x;
    const int wave = tid >> 6, lane = tid & 63;
    const int l15 = lane & 15, quad = lane >> 4;
    const int mbase = (wave >> 1) * 64;           // wave tile 64x64 within 128x128
    const int nbase = (wave & 1) * 64;

    // XCD rectangle: 16 qt x 16 kt per XCD (Q 1.31 MB + K 2.62 MB ~ L2-resident).
    const int b = (int)blockIdx.x;                // 512 blocks: 64 qt x 8 kt-groups
    const int xcd = b & 7;
    const int j = b >> 3;                         // 0..63
    const int qt = (xcd >> 1) * 16 + (j & 15);
    const int ktbase = (xcd & 1) * 32 + (j >> 4) * 8;   // 8 kt tiles per block
    const int q0 = qt * 128;

    // Q frags resident in VGPRs: 5 chunks x 4 mt x (h,l) = 160 VGPRs
    half8 qh[NCH][4], ql[NCH][4];
#pragma unroll
    for (int c = 0; c < NCH; ++c)
#pragma unroll
        for (int mt = 0; mt < 4; ++mt) {
            int off = c * CST + (qt * 8 + (mbase >> 4) + mt) * 512 + lane * 8;
            qh[c][mt] = *(const half8*)(Qh + off);
            ql[c][mt] = *(const half8*)(Ql + off);
        }

    float rbv = 1e38f;                 // running best (tid<128 threads use it)
    int rbn = 0x7fffffff;

    for (int t = 0; t < 8; ++t) {
        const int kts = ktbase + t;
        f32x4 acc0[4][4], acc1[4][4];
#pragma unroll
        for (int i = 0; i < 4; ++i)
#pragma unroll
            for (int jj = 0; jj < 4; ++jj) {
                acc0[i][jj] = (f32x4)0.f;
                acc1[i][jj] = (f32x4)0.f;
            }

        const int kgrp = (kts * 8 + (nbase >> 4)) * 512 + lane * 8;
#pragma unroll
        for (int c = 0; c < NCH; ++c) {
            half8 bh[4], bl[4];
#pragma unroll
            for (int nt = 0; nt < 4; ++nt) {
                bh[nt] = *(const half8*)(Kh + c * CST + kgrp + nt * 512);
                bl[nt] = *(const half8*)(Kl + c * CST + kgrp + nt * 512);
            }
#pragma unroll
            for (int nt = 0; nt < 4; ++nt)
#pragma unroll
                for (int mt = 0; mt < 4; ++mt) {
                    acc0[mt][nt] = __builtin_amdgcn_mfma_f32_16x16x32_f16(qh[c][mt], bh[nt], acc0[mt][nt], 0, 0, 0);
                    acc1[mt][nt] = __builtin_amdgcn_mfma_f32_16x16x32_f16(qh[c][mt], bl[nt], acc1[mt][nt], 0, 0, 0);
                    acc1[mt][nt] = __builtin_amdgcn_mfma_f32_16x16x32_f16(ql[c][mt], bh[nt], acc1[mt][nt], 0, 0, 0);
                }
        }

        // epilogue: dist = kn - 2*(acc0 + acc1/2048); reduce 128x128 tile -> per-row best
        float knv[4];
        int nglob[4];
#pragma unroll
        for (int nt = 0; nt < 4; ++nt) {
            nglob[nt] = kts * 128 + nbase + nt * 16 + l15;
            knv[nt] = kn[nglob[nt]];
        }
        __syncthreads();   // previous tile's scan fully read before overwrite
#pragma unroll
        for (int mt = 0; mt < 4; ++mt)
#pragma unroll
            for (int r = 0; r < 4; ++r) {
                float bv = 1e38f;
                int bn = 0x7fffffff;
#pragma unroll
                for (int nt = 0; nt < 4; ++nt) {   // ascending n within lane -> strict <
                    float d = knv[nt] - 2.0f * (acc0[mt][nt][r] + acc1[mt][nt][r] * (1.0f / 2048.0f));
                    if (d < bv) { bv = d; bn = nglob[nt]; }
                }
                int m = mbase + mt * 16 + quad * 4 + r;    // C layout: row = quad*4 + reg
                int cidx = (nbase >> 2) + l15;             // 0..31
                redv[m * 33 + cidx] = bv;
                redi[m * 33 + cidx] = bn;
            }
        __syncthreads();

        if (tid < 128) {
            for (int t2 = 0; t2 < 32; ++t2) {     // tie-aware (lanes interleave n)
                float v = redv[tid * 33 + t2];
                int n = redi[tid * 33 + t2];
                if (v < rbv || (v == rbv && n < rbn)) { rbv = v; rbn = n; }
            }
        }
    }

    if (tid < 128) {
        unsigned u = __float_as_uint(rbv);
        u = (u & 0x80000000u) ? ~u : (u | 0x80000000u);   // order-preserving map
        unsigned long long pk = ((unsigned long long)u << 32) | (unsigned)rbn;
        atomicMin(&out[q0 + tid], pk);
    }
}

// ---------------- gather + fold (overlap-add mean) ----------------
__global__ void k_fold(const float* __restrict__ value,
                       const unsigned long long* __restrict__ fidx64,
                       float* __restrict__ out) {
    int t = blockIdx.x * 256 + threadIdx.x;   // 3*96*96 = 27648
    if (t >= 3 * IMG * IMG) return;
    int c = t / (IMG * IMG);
    int rem = t % (IMG * IMG);
    int Y = rem / IMG, X = rem % IMG;
    int i0 = max(0, Y - (HO - 1)), i1 = min(6, Y);
    int j0 = max(0, X - (HO - 1)), j1 = min(6, X);
    float s = 0.f;
    for (int i = i0; i <= i1; ++i)
        for (int j = j0; j <= j1; ++j) {
            int p = (Y - i) * HO + (X - j);
            int row = (int)(fidx64[p] & 0xFFFFFFFFull);
            s += value[row * DD + c * 49 + i * 7 + j];
        }
    float cnt = (float)((i1 - i0 + 1) * (j1 - j0 + 1));
    out[t] = s / cnt;
}

extern "C" void kernel_launch(void* const* d_in, const int* in_sizes, int n_in,
                              void* d_out, int out_size, void* d_ws, size_t ws_size,
                              hipStream_t stream) {
    const float* query = (const float*)d_in[0];
    const float* key   = (const float*)d_in[1];
    const float* value = (const float*)d_in[2];
    float* out = (float*)d_out;

    _Float16* Qh = (_Float16*)d_ws;           // ARRN f16 each
    _Float16* Ql = Qh + ARRN;
    _Float16* Kh = Ql + ARRN;
    _Float16* Kl = Kh + ARRN;
    float* kn = (float*)(Kl + ARRN);          // 8192 f32
    unsigned long long* fidx64 = (unsigned long long*)(kn + 8192);   // 8192 u64

    dim3 gp(768, 2);   // 640 split blocks + 128 fused-kn blocks (y==1)
    k_prep<<<gp, 256, 0, stream>>>(query, key, Qh, Ql, Kh, Kl, kn, fidx64);
    k_nn<<<512, 256, 0, stream>>>(Qh, Ql, Kh, Kl, kn, fidx64);
    k_fold<<<108, 256, 0, stream>>>(value, fidx64, out);
}